// Round 1
// baseline (852.717 us; speedup 1.0000x reference)
//
#include <hip/hip_runtime.h>

#define N_NODES 100000
#define F_IN 64
#define F_OUT 40

// ---------------- degree accumulation ----------------
__global__ void deg_kernel(const int* __restrict__ dst, int E, float* __restrict__ deg) {
    int e = blockIdx.x * blockDim.x + threadIdx.x;
    if (e < E) atomicAdd(&deg[dst[e]], 1.0f);
}

// dinv = rsqrt(deg + 1)   (self-loop contributes +1; deg >= 1 always)
__global__ void dinv_kernel(float* __restrict__ deg, int n) {
    int i = blockIdx.x * blockDim.x + threadIdx.x;
    if (i < n) deg[i] = rsqrtf(deg[i] + 1.0f);
}

// ---------------- projection y = x @ W^T  (no bias; bias added at the end) ----------------
__global__ __launch_bounds__(256) void proj_kernel(const float* __restrict__ x,
                                                   const float* __restrict__ W,
                                                   float* __restrict__ y, int n) {
    __shared__ float Ws[F_OUT * F_IN];
    for (int i = threadIdx.x; i < F_OUT * F_IN; i += blockDim.x) Ws[i] = W[i];
    __syncthreads();

    int node = blockIdx.x * blockDim.x + threadIdx.x;
    if (node >= n) return;

    const float4* xp  = (const float4*)(x + (size_t)node * F_IN);
    const float4* Ws4 = (const float4*)Ws;

    float acc[F_OUT];
#pragma unroll
    for (int c = 0; c < F_OUT; ++c) acc[c] = 0.0f;

#pragma unroll
    for (int f4 = 0; f4 < F_IN / 4; ++f4) {
        float4 xv = xp[f4];
#pragma unroll
        for (int c = 0; c < F_OUT; ++c) {
            float4 w = Ws4[c * (F_IN / 4) + f4];   // wave-uniform LDS broadcast
            acc[c] += xv.x * w.x + xv.y * w.y + xv.z * w.z + xv.w * w.w;
        }
    }

    float4* yp = (float4*)(y + (size_t)node * F_OUT);   // node*160B: 16B aligned
#pragma unroll
    for (int c4 = 0; c4 < F_OUT / 4; ++c4) {
        float4 v;
        v.x = acc[4 * c4 + 0]; v.y = acc[4 * c4 + 1];
        v.z = acc[4 * c4 + 2]; v.w = acc[4 * c4 + 3];
        yp[c4] = v;
    }
}

// ---------------- self-loop init: ynew = dinv^2 * ycur  (float4 over N*F_OUT) ----------------
__global__ void selfloop_init_kernel(const float* __restrict__ ycur,
                                     const float* __restrict__ dinv,
                                     float* __restrict__ ynew, int n4) {
    int i = blockIdx.x * blockDim.x + threadIdx.x;
    if (i >= n4) return;
    int node = i / (F_OUT / 4);          // 4 consecutive floats never cross a 40-float row
    float d = dinv[node];
    float s = d * d;
    float4 v = ((const float4*)ycur)[i];
    v.x *= s; v.y *= s; v.z *= s; v.w *= s;
    ((float4*)ynew)[i] = v;
}

// ---------------- edge scatter: ynew[dst] += dinv[src]*dinv[dst]*ycur[src] ----------------
__global__ void scatter_kernel(const int* __restrict__ src, const int* __restrict__ dst,
                               const float* __restrict__ dinv,
                               const float* __restrict__ ycur, float* __restrict__ ynew,
                               long long total) {
    long long t = (long long)blockIdx.x * blockDim.x + threadIdx.x;
    if (t >= total) return;
    int e = (int)(t / F_OUT);
    int f = (int)(t - (long long)e * F_OUT);
    int r = src[e];
    int c = dst[e];
    float nrm = dinv[r] * dinv[c];
    float val = nrm * ycur[(size_t)r * F_OUT + f];
    atomicAdd(&ynew[(size_t)c * F_OUT + f], val);
}

// ---------------- in-place bias + log_softmax over 40 classes ----------------
__global__ void logsoftmax_kernel(float* __restrict__ out, const float* __restrict__ bias, int n) {
    int node = blockIdx.x * blockDim.x + threadIdx.x;
    if (node >= n) return;
    float4* p = (float4*)(out + (size_t)node * F_OUT);
    float v[F_OUT];
    float mx = -1e30f;
#pragma unroll
    for (int c4 = 0; c4 < F_OUT / 4; ++c4) {
        float4 t = p[c4];
        v[4 * c4 + 0] = t.x + bias[4 * c4 + 0];
        v[4 * c4 + 1] = t.y + bias[4 * c4 + 1];
        v[4 * c4 + 2] = t.z + bias[4 * c4 + 2];
        v[4 * c4 + 3] = t.w + bias[4 * c4 + 3];
    }
#pragma unroll
    for (int c = 0; c < F_OUT; ++c) mx = fmaxf(mx, v[c]);
    float se = 0.0f;
#pragma unroll
    for (int c = 0; c < F_OUT; ++c) se += __expf(v[c] - mx);
    float lse = mx + __logf(se);
#pragma unroll
    for (int c4 = 0; c4 < F_OUT / 4; ++c4) {
        float4 t;
        t.x = v[4 * c4 + 0] - lse; t.y = v[4 * c4 + 1] - lse;
        t.z = v[4 * c4 + 2] - lse; t.w = v[4 * c4 + 3] - lse;
        p[c4] = t;
    }
}

extern "C" void kernel_launch(void* const* d_in, const int* in_sizes, int n_in,
                              void* d_out, int out_size, void* d_ws, size_t ws_size,
                              hipStream_t stream) {
    const float* x  = (const float*)d_in[0];
    const int*   ei = (const int*)d_in[1];
    const float* W  = (const float*)d_in[2];
    const float* b  = (const float*)d_in[3];

    const int N = in_sizes[0] / F_IN;        // 100000
    const int E = in_sizes[1] / 2;           // 1280000
    const int* src = ei;
    const int* dst = ei + E;

    // workspace layout: deg/dinv [N floats, rounded to 512KB] | yA [N*F_OUT floats]
    float* deg = (float*)d_ws;
    float* yA  = (float*)((char*)d_ws + 512 * 1024);
    float* yB  = (float*)d_out;              // d_out (N*F_OUT floats) doubles as ping-pong buffer

    // 1) degrees -> dinv
    hipMemsetAsync(deg, 0, (size_t)N * sizeof(float), stream);
    deg_kernel<<<(E + 255) / 256, 256, 0, stream>>>(dst, E, deg);
    dinv_kernel<<<(N + 255) / 256, 256, 0, stream>>>(deg, N);

    // 2) projection y = x @ W^T  (into yA)
    proj_kernel<<<(N + 255) / 256, 256, 0, stream>>>(x, W, yA, N);

    // 3) three propagation hops: yA -> yB -> yA -> yB
    const int n4 = N * F_OUT / 4;
    const long long total = (long long)E * F_OUT;
    const int sg = (int)((total + 255) / 256);

    selfloop_init_kernel<<<(n4 + 255) / 256, 256, 0, stream>>>(yA, deg, yB, n4);
    scatter_kernel<<<sg, 256, 0, stream>>>(src, dst, deg, yA, yB, total);

    selfloop_init_kernel<<<(n4 + 255) / 256, 256, 0, stream>>>(yB, deg, yA, n4);
    scatter_kernel<<<sg, 256, 0, stream>>>(src, dst, deg, yB, yA, total);

    selfloop_init_kernel<<<(n4 + 255) / 256, 256, 0, stream>>>(yA, deg, yB, n4);
    scatter_kernel<<<sg, 256, 0, stream>>>(src, dst, deg, yA, yB, total);

    // 4) bias + log_softmax in place on d_out
    logsoftmax_kernel<<<(N + 255) / 256, 256, 0, stream>>>(yB, b, N);
}

// Round 2
// 614.521 us; speedup vs baseline: 1.3876x; 1.3876x over previous
//
#include <hip/hip_runtime.h>

#define F_IN 64
#define F_OUT 40
#define F4 (F_OUT / 4)   // 10 float4 per row

// ---------------- degree histogram (int) ----------------
__global__ void deg_count_kernel(const int* __restrict__ dst, int E, int* __restrict__ deg) {
    int e = blockIdx.x * blockDim.x + threadIdx.x;
    if (e < E) atomicAdd(&deg[dst[e]], 1);
}

// dinv = rsqrt(deg + 1)   (self-loop contributes +1)
__global__ void dinv_kernel(const int* __restrict__ deg, float* __restrict__ dinv, int n) {
    int i = blockIdx.x * blockDim.x + threadIdx.x;
    if (i < n) dinv[i] = rsqrtf((float)deg[i] + 1.0f);
}

// ---------------- single-block exclusive scan -> rowptr + cursor ----------------
__global__ __launch_bounds__(1024) void scan_kernel(const int* __restrict__ deg,
                                                    int* __restrict__ rowptr,
                                                    int* __restrict__ cursor, int n) {
    __shared__ int sums[1024];
    int tid = threadIdx.x;
    int chunk = (n + 1023) / 1024;
    int beg = tid * chunk;
    int end = min(beg + chunk, n);
    int s = 0;
    for (int i = beg; i < end; ++i) s += deg[i];
    sums[tid] = s;
    __syncthreads();
    // inclusive Hillis-Steele scan over 1024 partials
    for (int off = 1; off < 1024; off <<= 1) {
        int v = 0;
        if (tid >= off) v = sums[tid - off];
        __syncthreads();
        if (tid >= off) sums[tid] += v;
        __syncthreads();
    }
    if (tid == 0) rowptr[n] = sums[1023];   // total edge count
    int prefix = (tid == 0) ? 0 : sums[tid - 1];
    for (int i = beg; i < end; ++i) {
        rowptr[i] = prefix;
        cursor[i] = prefix;
        prefix += deg[i];
    }
}

// ---------------- reorder edges by dst; precompute per-edge norm ----------------
__global__ void reorder_kernel(const int* __restrict__ src, const int* __restrict__ dst,
                               const float* __restrict__ dinv, int* __restrict__ cursor,
                               int* __restrict__ src_sorted, float* __restrict__ norm_sorted,
                               int E) {
    int e = blockIdx.x * blockDim.x + threadIdx.x;
    if (e >= E) return;
    int r = src[e];
    int c = dst[e];
    int pos = atomicAdd(&cursor[c], 1);
    src_sorted[pos] = r;
    norm_sorted[pos] = dinv[r] * dinv[c];
}

// ---------------- projection y = x @ W^T ----------------
__global__ __launch_bounds__(256) void proj_kernel(const float* __restrict__ x,
                                                   const float* __restrict__ W,
                                                   float* __restrict__ y, int n) {
    __shared__ float Ws[F_OUT * F_IN];
    for (int i = threadIdx.x; i < F_OUT * F_IN; i += blockDim.x) Ws[i] = W[i];
    __syncthreads();

    int node = blockIdx.x * blockDim.x + threadIdx.x;
    if (node >= n) return;

    const float4* xp  = (const float4*)(x + (size_t)node * F_IN);
    const float4* Ws4 = (const float4*)Ws;

    float acc[F_OUT];
#pragma unroll
    for (int c = 0; c < F_OUT; ++c) acc[c] = 0.0f;

#pragma unroll
    for (int f4 = 0; f4 < F_IN / 4; ++f4) {
        float4 xv = xp[f4];
#pragma unroll
        for (int c = 0; c < F_OUT; ++c) {
            float4 w = Ws4[c * (F_IN / 4) + f4];
            acc[c] += xv.x * w.x + xv.y * w.y + xv.z * w.z + xv.w * w.w;
        }
    }

    float4* yp = (float4*)(y + (size_t)node * F_OUT);
#pragma unroll
    for (int c4 = 0; c4 < F4; ++c4) {
        float4 v;
        v.x = acc[4 * c4 + 0]; v.y = acc[4 * c4 + 1];
        v.z = acc[4 * c4 + 2]; v.w = acc[4 * c4 + 3];
        yp[c4] = v;
    }
}

// ---------------- pull-based propagation, self-loop fused ----------------
// thread t handles (node = t/10, f4 = t%10): one float4 of the output row.
__global__ __launch_bounds__(256) void propagate_kernel(const int* __restrict__ rowptr,
                                                        const int* __restrict__ srcs,
                                                        const float* __restrict__ norms,
                                                        const float* __restrict__ dinv,
                                                        const float* __restrict__ ycur,
                                                        float* __restrict__ ynew, int n) {
    int t = blockIdx.x * blockDim.x + threadIdx.x;
    int node = t / F4;
    int f4 = t - node * F4;
    if (node >= n) return;

    int beg = rowptr[node];
    int end = rowptr[node + 1];

    float4 acc = make_float4(0.f, 0.f, 0.f, 0.f);
    for (int i = beg; i < end; ++i) {
        int s = srcs[i];
        float nrm = norms[i];
        float4 v = ((const float4*)(ycur + (size_t)s * F_OUT))[f4];
        acc.x += nrm * v.x; acc.y += nrm * v.y;
        acc.z += nrm * v.z; acc.w += nrm * v.w;
    }
    // self loop: dinv[node]^2 * ycur[node]
    float d = dinv[node];
    float ds = d * d;
    float4 sv = ((const float4*)(ycur + (size_t)node * F_OUT))[f4];
    acc.x += ds * sv.x; acc.y += ds * sv.y;
    acc.z += ds * sv.z; acc.w += ds * sv.w;

    ((float4*)(ynew + (size_t)node * F_OUT))[f4] = acc;
}

// ---------------- in-place bias + log_softmax over 40 classes ----------------
__global__ void logsoftmax_kernel(float* __restrict__ out, const float* __restrict__ bias, int n) {
    int node = blockIdx.x * blockDim.x + threadIdx.x;
    if (node >= n) return;
    float4* p = (float4*)(out + (size_t)node * F_OUT);
    float v[F_OUT];
    float mx = -1e30f;
#pragma unroll
    for (int c4 = 0; c4 < F4; ++c4) {
        float4 t = p[c4];
        v[4 * c4 + 0] = t.x + bias[4 * c4 + 0];
        v[4 * c4 + 1] = t.y + bias[4 * c4 + 1];
        v[4 * c4 + 2] = t.z + bias[4 * c4 + 2];
        v[4 * c4 + 3] = t.w + bias[4 * c4 + 3];
    }
#pragma unroll
    for (int c = 0; c < F_OUT; ++c) mx = fmaxf(mx, v[c]);
    float se = 0.0f;
#pragma unroll
    for (int c = 0; c < F_OUT; ++c) se += __expf(v[c] - mx);
    float lse = mx + __logf(se);
#pragma unroll
    for (int c4 = 0; c4 < F4; ++c4) {
        float4 t;
        t.x = v[4 * c4 + 0] - lse; t.y = v[4 * c4 + 1] - lse;
        t.z = v[4 * c4 + 2] - lse; t.w = v[4 * c4 + 3] - lse;
        p[c4] = t;
    }
}

extern "C" void kernel_launch(void* const* d_in, const int* in_sizes, int n_in,
                              void* d_out, int out_size, void* d_ws, size_t ws_size,
                              hipStream_t stream) {
    const float* x  = (const float*)d_in[0];
    const int*   ei = (const int*)d_in[1];
    const float* W  = (const float*)d_in[2];
    const float* b  = (const float*)d_in[3];

    const int N = in_sizes[0] / F_IN;        // 100000
    const int E = in_sizes[1] / 2;           // 1280000
    const int* src = ei;
    const int* dst = ei + E;

    // ---- workspace layout (256B-aligned slabs) ----
    char* base = (char*)d_ws;
    size_t off = 0;
    auto alloc = [&](size_t bytes) {
        char* p = base + off;
        off = (off + bytes + 255) & ~(size_t)255;
        return p;
    };
    int*   deg_i       = (int*)  alloc((size_t)N * 4);
    float* dinv        = (float*)alloc((size_t)N * 4);
    int*   rowptr      = (int*)  alloc((size_t)(N + 1) * 4);
    int*   cursor      = (int*)  alloc((size_t)N * 4);
    int*   src_sorted  = (int*)  alloc((size_t)E * 4);
    float* norm_sorted = (float*)alloc((size_t)E * 4);
    float* yA          = (float*)alloc((size_t)N * F_OUT * 4);
    float* yB          = (float*)d_out;      // d_out doubles as ping-pong buffer

    // 1) CSR build
    hipMemsetAsync(deg_i, 0, (size_t)N * sizeof(int), stream);
    deg_count_kernel<<<(E + 255) / 256, 256, 0, stream>>>(dst, E, deg_i);
    dinv_kernel<<<(N + 255) / 256, 256, 0, stream>>>(deg_i, dinv, N);
    scan_kernel<<<1, 1024, 0, stream>>>(deg_i, rowptr, cursor, N);
    reorder_kernel<<<(E + 255) / 256, 256, 0, stream>>>(src, dst, dinv, cursor,
                                                        src_sorted, norm_sorted, E);

    // 2) projection y = x @ W^T  (into yA)
    proj_kernel<<<(N + 255) / 256, 256, 0, stream>>>(x, W, yA, N);

    // 3) three pull-based hops (self-loop fused): yA -> yB -> yA -> yB
    const int pt = N * F4;                   // 1M threads
    const int pg = (pt + 255) / 256;
    propagate_kernel<<<pg, 256, 0, stream>>>(rowptr, src_sorted, norm_sorted, dinv, yA, yB, N);
    propagate_kernel<<<pg, 256, 0, stream>>>(rowptr, src_sorted, norm_sorted, dinv, yB, yA, N);
    propagate_kernel<<<pg, 256, 0, stream>>>(rowptr, src_sorted, norm_sorted, dinv, yA, yB, N);

    // 4) bias + log_softmax in place on d_out
    logsoftmax_kernel<<<(N + 255) / 256, 256, 0, stream>>>(yB, b, N);
}

// Round 3
// 392.789 us; speedup vs baseline: 2.1709x; 1.5645x over previous
//
#include <hip/hip_runtime.h>

#define F_IN 64
#define F_OUT 40
#define F4 (F_OUT / 4)        // 10 float4 per row

#define SCAN_BLK 256
#define SCAN_ELEMS 4
#define SCAN_TILE (SCAN_BLK * SCAN_ELEMS)   // 1024 elems per block

// ---------------- degree histogram (int) ----------------
__global__ void deg_count_kernel(const int* __restrict__ dst, int E, int* __restrict__ deg) {
    int e = blockIdx.x * blockDim.x + threadIdx.x;
    if (e < E) atomicAdd(&deg[dst[e]], 1);
}

// dinv = rsqrt(deg + 1)   (self-loop contributes +1)
__global__ void dinv_kernel(const int* __restrict__ deg, float* __restrict__ dinv, int n) {
    int i = blockIdx.x * blockDim.x + threadIdx.x;
    if (i < n) dinv[i] = rsqrtf((float)deg[i] + 1.0f);
}

// ---------------- hierarchical scan: A) per-block reduce ----------------
__global__ __launch_bounds__(SCAN_BLK) void scan_a_kernel(const int* __restrict__ deg,
                                                          int* __restrict__ bsum, int n) {
    __shared__ int s[SCAN_BLK];
    int tid = threadIdx.x;
    int base = blockIdx.x * SCAN_TILE + tid * SCAN_ELEMS;
    int local = 0;
#pragma unroll
    for (int k = 0; k < SCAN_ELEMS; ++k) {
        int i = base + k;
        if (i < n) local += deg[i];
    }
    s[tid] = local;
    __syncthreads();
    for (int off = SCAN_BLK / 2; off > 0; off >>= 1) {
        if (tid < off) s[tid] += s[tid + off];
        __syncthreads();
    }
    if (tid == 0) bsum[blockIdx.x] = s[0];
}

// ---------------- B) single-block scan of <=256 partials -> exclusive offsets ----------------
__global__ __launch_bounds__(256) void scan_b_kernel(int* __restrict__ bsum,
                                                     int* __restrict__ total_out, int nb) {
    __shared__ int s[256];
    int tid = threadIdx.x;
    int v = (tid < nb) ? bsum[tid] : 0;
    s[tid] = v;
    __syncthreads();
    for (int off = 1; off < 256; off <<= 1) {
        int t = (tid >= off) ? s[tid - off] : 0;
        __syncthreads();
        s[tid] += t;
        __syncthreads();
    }
    if (tid < nb) bsum[tid] = s[tid] - v;     // exclusive block offset
    if (tid == 255) *total_out = s[255];      // rowptr[n]
}

// ---------------- C) per-block local scan + offset -> rowptr & cursor ----------------
__global__ __launch_bounds__(SCAN_BLK) void scan_c_kernel(const int* __restrict__ deg,
                                                          const int* __restrict__ boff,
                                                          int* __restrict__ rowptr,
                                                          int* __restrict__ cursor, int n) {
    __shared__ int s[SCAN_BLK];
    int tid = threadIdx.x;
    int base = blockIdx.x * SCAN_TILE + tid * SCAN_ELEMS;
    int vals[SCAN_ELEMS];
    int local = 0;
#pragma unroll
    for (int k = 0; k < SCAN_ELEMS; ++k) {
        int i = base + k;
        vals[k] = (i < n) ? deg[i] : 0;
        local += vals[k];
    }
    s[tid] = local;
    __syncthreads();
    for (int off = 1; off < SCAN_BLK; off <<= 1) {
        int t = (tid >= off) ? s[tid - off] : 0;
        __syncthreads();
        s[tid] += t;
        __syncthreads();
    }
    int prefix = boff[blockIdx.x] + s[tid] - local;   // exclusive prefix for this thread
#pragma unroll
    for (int k = 0; k < SCAN_ELEMS; ++k) {
        int i = base + k;
        if (i < n) {
            rowptr[i] = prefix;
            cursor[i] = prefix;
            prefix += vals[k];
        }
    }
}

// ---------------- reorder edges by dst; record = {src, norm} in one 8B write ----------------
__global__ void reorder_kernel(const int* __restrict__ src, const int* __restrict__ dst,
                               const float* __restrict__ dinv, int* __restrict__ cursor,
                               int2* __restrict__ edges, int E) {
    int e = blockIdx.x * blockDim.x + threadIdx.x;
    if (e >= E) return;
    int r = src[e];
    int c = dst[e];
    int pos = atomicAdd(&cursor[c], 1);
    float nrm = dinv[r] * dinv[c];
    int2 rec;
    rec.x = r;
    rec.y = __float_as_int(nrm);
    edges[pos] = rec;
}

// ---------------- projection y = x @ W^T ----------------
__global__ __launch_bounds__(256) void proj_kernel(const float* __restrict__ x,
                                                   const float* __restrict__ W,
                                                   float* __restrict__ y, int n) {
    __shared__ float Ws[F_OUT * F_IN];
    for (int i = threadIdx.x; i < F_OUT * F_IN; i += blockDim.x) Ws[i] = W[i];
    __syncthreads();

    int node = blockIdx.x * blockDim.x + threadIdx.x;
    if (node >= n) return;

    const float4* xp  = (const float4*)(x + (size_t)node * F_IN);
    const float4* Ws4 = (const float4*)Ws;

    float acc[F_OUT];
#pragma unroll
    for (int c = 0; c < F_OUT; ++c) acc[c] = 0.0f;

#pragma unroll
    for (int f4 = 0; f4 < F_IN / 4; ++f4) {
        float4 xv = xp[f4];
#pragma unroll
        for (int c = 0; c < F_OUT; ++c) {
            float4 w = Ws4[c * (F_IN / 4) + f4];
            acc[c] += xv.x * w.x + xv.y * w.y + xv.z * w.z + xv.w * w.w;
        }
    }

    float4* yp = (float4*)(y + (size_t)node * F_OUT);
#pragma unroll
    for (int c4 = 0; c4 < F4; ++c4) {
        float4 v;
        v.x = acc[4 * c4 + 0]; v.y = acc[4 * c4 + 1];
        v.z = acc[4 * c4 + 2]; v.w = acc[4 * c4 + 3];
        yp[c4] = v;
    }
}

// ---------------- pull-based propagation, self-loop fused ----------------
// thread t handles (node = t/10, f4 = t%10): one float4 of the output row.
__global__ __launch_bounds__(256) void propagate_kernel(const int* __restrict__ rowptr,
                                                        const int2* __restrict__ edges,
                                                        const float* __restrict__ dinv,
                                                        const float* __restrict__ ycur,
                                                        float* __restrict__ ynew, int n) {
    int t = blockIdx.x * blockDim.x + threadIdx.x;
    int node = t / F4;
    int f4 = t - node * F4;
    if (node >= n) return;

    int beg = rowptr[node];
    int end = rowptr[node + 1];

    float4 acc = make_float4(0.f, 0.f, 0.f, 0.f);
    for (int i = beg; i < end; ++i) {
        int2 rec = edges[i];
        int s = rec.x;
        float nrm = __int_as_float(rec.y);
        float4 v = ((const float4*)(ycur + (size_t)s * F_OUT))[f4];
        acc.x += nrm * v.x; acc.y += nrm * v.y;
        acc.z += nrm * v.z; acc.w += nrm * v.w;
    }
    // self loop: dinv[node]^2 * ycur[node]
    float d = dinv[node];
    float ds = d * d;
    float4 sv = ((const float4*)(ycur + (size_t)node * F_OUT))[f4];
    acc.x += ds * sv.x; acc.y += ds * sv.y;
    acc.z += ds * sv.z; acc.w += ds * sv.w;

    ((float4*)(ynew + (size_t)node * F_OUT))[f4] = acc;
}

// ---------------- in-place bias + log_softmax over 40 classes ----------------
__global__ void logsoftmax_kernel(float* __restrict__ out, const float* __restrict__ bias, int n) {
    int node = blockIdx.x * blockDim.x + threadIdx.x;
    if (node >= n) return;
    float4* p = (float4*)(out + (size_t)node * F_OUT);
    float v[F_OUT];
    float mx = -1e30f;
#pragma unroll
    for (int c4 = 0; c4 < F4; ++c4) {
        float4 t = p[c4];
        v[4 * c4 + 0] = t.x + bias[4 * c4 + 0];
        v[4 * c4 + 1] = t.y + bias[4 * c4 + 1];
        v[4 * c4 + 2] = t.z + bias[4 * c4 + 2];
        v[4 * c4 + 3] = t.w + bias[4 * c4 + 3];
    }
#pragma unroll
    for (int c = 0; c < F_OUT; ++c) mx = fmaxf(mx, v[c]);
    float se = 0.0f;
#pragma unroll
    for (int c = 0; c < F_OUT; ++c) se += __expf(v[c] - mx);
    float lse = mx + __logf(se);
#pragma unroll
    for (int c4 = 0; c4 < F4; ++c4) {
        float4 t;
        t.x = v[4 * c4 + 0] - lse; t.y = v[4 * c4 + 1] - lse;
        t.z = v[4 * c4 + 2] - lse; t.w = v[4 * c4 + 3] - lse;
        p[c4] = t;
    }
}

extern "C" void kernel_launch(void* const* d_in, const int* in_sizes, int n_in,
                              void* d_out, int out_size, void* d_ws, size_t ws_size,
                              hipStream_t stream) {
    const float* x  = (const float*)d_in[0];
    const int*   ei = (const int*)d_in[1];
    const float* W  = (const float*)d_in[2];
    const float* b  = (const float*)d_in[3];

    const int N = in_sizes[0] / F_IN;        // 100000
    const int E = in_sizes[1] / 2;           // 1280000
    const int* src = ei;
    const int* dst = ei + E;

    // ---- workspace layout (256B-aligned slabs) ----
    char* base = (char*)d_ws;
    size_t off = 0;
    auto alloc = [&](size_t bytes) {
        char* p = base + off;
        off = (off + bytes + 255) & ~(size_t)255;
        return p;
    };
    int*   deg_i  = (int*)  alloc((size_t)N * 4);
    float* dinv   = (float*)alloc((size_t)N * 4);
    int*   rowptr = (int*)  alloc((size_t)(N + 1) * 4);
    int*   cursor = (int*)  alloc((size_t)N * 4);
    int*   bsum   = (int*)  alloc(256 * 4);
    int2*  edges  = (int2*) alloc((size_t)E * 8);
    float* yA     = (float*)alloc((size_t)N * F_OUT * 4);
    float* yB     = (float*)d_out;           // d_out doubles as ping-pong buffer

    const int nb = (N + SCAN_TILE - 1) / SCAN_TILE;   // 98 blocks

    // 1) CSR build
    hipMemsetAsync(deg_i, 0, (size_t)N * sizeof(int), stream);
    deg_count_kernel<<<(E + 255) / 256, 256, 0, stream>>>(dst, E, deg_i);
    dinv_kernel<<<(N + 255) / 256, 256, 0, stream>>>(deg_i, dinv, N);
    scan_a_kernel<<<nb, SCAN_BLK, 0, stream>>>(deg_i, bsum, N);
    scan_b_kernel<<<1, 256, 0, stream>>>(bsum, rowptr + N, nb);
    scan_c_kernel<<<nb, SCAN_BLK, 0, stream>>>(deg_i, bsum, rowptr, cursor, N);
    reorder_kernel<<<(E + 255) / 256, 256, 0, stream>>>(src, dst, dinv, cursor, edges, E);

    // 2) projection y = x @ W^T  (into yA)
    proj_kernel<<<(N + 255) / 256, 256, 0, stream>>>(x, W, yA, N);

    // 3) three pull-based hops (self-loop fused): yA -> yB -> yA -> yB
    const int pt = N * F4;                   // 1M threads
    const int pg = (pt + 255) / 256;
    propagate_kernel<<<pg, 256, 0, stream>>>(rowptr, edges, dinv, yA, yB, N);
    propagate_kernel<<<pg, 256, 0, stream>>>(rowptr, edges, dinv, yB, yA, N);
    propagate_kernel<<<pg, 256, 0, stream>>>(rowptr, edges, dinv, yA, yB, N);

    // 4) bias + log_softmax in place on d_out
    logsoftmax_kernel<<<(N + 255) / 256, 256, 0, stream>>>(yB, b, N);
}